// Round 7
// baseline (105.713 us; speedup 1.0000x reference)
//
#include <hip/hip_runtime.h>

typedef int v4i  __attribute__((ext_vector_type(4)));
typedef int v16i __attribute__((ext_vector_type(16)));

// ---- problem constants ----
#define N_IMG   32
#define C_IN    256
#define HWDIM   56
#define HW2     3136            // 56*56
#define OUT_TOT 25690112        // 32*256*56*56
#define OUT_NSTR 802816         // 256*3136

// padded NHWC int8, PXB bytes per pixel (256 data + 16 pad; uniform 2-deep banks)
#define PXB     272
#define PPI     3364            // 58*58 padded pixels per image
#define XP_IMG  915008          // PPI*PXB bytes per image
// packed weights: [cb2:8][tap:9][kb:8][lane:64][16B]
#define WP_CB2STR 73728
#define WP_BYTES  589824ull

// main-kernel tiling: 256 spatial px per block, X window 384 px
#define S_TILE  256
#define TILES_PER_IMG 13
#define WIN_B   104448          // 384*272
#define XP_SLACK WIN_B
#define WPHB    16384           // one W phase buffer: 256co x 64ci
#define LDSB    (WIN_B + 2*WPHB)   // 137216

// ---------- pre-pass A: x NCHW int32 -> padded NHWC int8 (272B/pixel) ----------
__global__ void dc_x_to_nhwc(const int* __restrict__ x, unsigned int* __restrict__ x8,
                             int n0) {
    __shared__ unsigned int lds[64 * 65];
    const int t = threadIdx.x;
    const int w = t & 63, q = t >> 6;
    const int nl = blockIdx.x / HWDIM, h = blockIdx.x % HWDIM;

    if (w < HWDIM) {
        const int* xb = x + (size_t)(n0 + nl) * OUT_NSTR + h * HWDIM + w;
        #pragma unroll
        for (int it = 0; it < 16; ++it) {
            const int cg4 = q * 16 + it;
            const int ci0 = cg4 * 4;
            unsigned v  =  ((unsigned)xb[(ci0 + 0) * HW2] & 0xff);
            v |= ((unsigned)xb[(ci0 + 1) * HW2] & 0xff) << 8;
            v |= ((unsigned)xb[(ci0 + 2) * HW2] & 0xff) << 16;
            v |= ((unsigned)xb[(ci0 + 3) * HW2] & 0xff) << 24;
            lds[w * 65 + cg4] = v;
        }
    }
    __syncthreads();
    unsigned int* ob = x8 + (size_t)nl * (PPI * (PXB / 4)) + ((h + 1) * 58 + 1) * (PXB / 4);
    #pragma unroll
    for (int it = 0; it < 14; ++it) {
        const int f = it * 256 + t;
        const int w2 = f >> 6, cg = f & 63;
        if (w2 < HWDIM) ob[w2 * (PXB / 4) + cg] = lds[w2 * 65 + cg];
    }
}

// ---------- halo-ring zero ----------
__global__ void dc_halo(unsigned int* __restrict__ x8) {
    const int nl = blockIdx.x;
    const int t = threadIdx.x;
    if (t < 228) {
        int h, w;
        if (t < 58)       { h = 0;        w = t; }
        else if (t < 116) { h = 57;       w = t - 58; }
        else if (t < 172) { h = t - 115;  w = 0; }
        else              { h = t - 171;  w = 57; }
        unsigned int* p = x8 + ((size_t)nl * PPI + h * 58 + w) * (PXB / 4);
        #pragma unroll
        for (int i = 0; i < PXB / 4; ++i) p[i] = 0;
    }
}

// ---------- pre-pass B: pack weights into per-lane fragment order ----------
__global__ void dc_pack_w(const int* __restrict__ wt, unsigned int* __restrict__ wp) {
    const int tid = blockIdx.x * 256 + threadIdx.x;  // < 147456
    const int jq = tid & 3;
    const int l  = (tid >> 2) & 63;
    const int kb = (tid >> 8) & 7;
    const int r  = tid >> 11;          // 0..71
    const int t  = r % 9;
    const int cb2 = r / 9;             // 0..7
    const int co  = cb2 * 32 + (l & 31);
    const int ci0 = kb * 32 + (l >> 5) * 16 + jq * 4;
    const int kh = t / 3, kw = t - kh * 3;
    unsigned v = 0;
    #pragma unroll
    for (int k = 0; k < 4; ++k) {
        unsigned b = (unsigned)wt[((co * C_IN + ci0 + k) * 3 + kh) * 3 + kw];
        v |= (b & 0xff) << (8 * k);
    }
    wp[tid] = v;
}

__device__ __forceinline__ void gll16(const char* g, char* l) {
    __builtin_amdgcn_global_load_lds(
        (const __attribute__((address_space(1))) unsigned int*)g,
        (__attribute__((address_space(3))) unsigned int*)l, 16, 0, 0);
}

// ---------- main kernel: 256co x 256s; X resident in LDS; W phased via LDS pp --
// 8 waves co4 x s2, wave = 64co x 128s (acc[2][4]).
// phase p = (tap, kb-pair): 36 phases; stage W(p+1) async, one barrier/phase.
__global__ __launch_bounds__(512, 2) void dc_mfma(const char* __restrict__ x8,
                                                  const char* __restrict__ wp,
                                                  int* __restrict__ out, int nwg) {
    extern __shared__ __align__(16) char xs[];
    char* wbuf = xs + WIN_B;

    // bijective XCD swizzle (m204)
    const int bid = blockIdx.x;
    const int q = nwg >> 3, r = nwg & 7;
    const int xcd = bid & 7, bidx = bid >> 3;
    const int wgid = (xcd < r ? xcd * (q + 1) : r * (q + 1) + (xcd - r) * q) + bidx;

    const int nl = wgid / TILES_PER_IMG, st = wgid - nl * TILES_PER_IMG;

    const int tid = threadIdx.x;
    const int l = tid & 63, wid = tid >> 6;
    const int lane31 = l & 31, hi = l >> 5;
    const int cg = wid & 3, sg = wid >> 2;     // co-group (64co), s-group (128s)

    // ---- stage X window: pixels [p0, p0+384) of this image ----
    const int hw0 = st * S_TILE;
    const int p0 = (hw0 / HWDIM + 1) * 58 + (hw0 % HWDIM) + 1 - 59;
    const char* gsrc = x8 + (size_t)nl * XP_IMG + (size_t)p0 * PXB;

    #pragma unroll
    for (int c = 0; c < 13; ++c) {             // 13*512*16 >= 104448
        const int off = (c * 512 + tid) * 16;
        if (off < WIN_B) gll16(gsrc + off, xs + off);
    }

    // ---- W staging bases (per-thread, loop adds literal phase offsets) ----
    // phase buffer layout: [cb2:8][kbl:2][lane:64][16B] = 16384 B
    const int idx0 = tid, idx1 = 512 + tid;
    const char* wsrc0 = wp + (idx0 >> 7) * WP_CB2STR + ((idx0 >> 6) & 1) * 1024 + (idx0 & 63) * 16;
    const char* wsrc1 = wp + (idx1 >> 7) * WP_CB2STR + ((idx1 >> 6) & 1) * 1024 + (idx1 & 63) * 16;
    char* wdst0 = wbuf + idx0 * 16;
    char* wdst1 = wbuf + idx1 * 16;

    // stage W phase 0 (t=0, kp=0) into buffer 0
    gll16(wsrc0, wdst0);
    gll16(wsrc1, wdst1);

    // ---- per-s-fragment setup while DMA flies ----
    int breg[4], outb[4];
    bool val[4];
    #pragma unroll
    for (int ni = 0; ni < 4; ++ni) {
        int hw = hw0 + sg * 128 + ni * 32 + lane31;
        val[ni] = (hw < HW2);
        if (!val[ni]) hw = HW2 - 1;
        const int p = (hw / HWDIM + 1) * 58 + (hw % HWDIM) + 1;
        breg[ni] = (p - p0) * PXB + hi * 16 - 16048;
        outb[ni] = nl * OUT_NSTR + hw;
    }

    const int xoffp[9] = {
        16048 - 59 * PXB, 16048 - 58 * PXB, 16048 - 57 * PXB,
        16048 - 1 * PXB,  16048,            16048 + 1 * PXB,
        16048 + 57 * PXB, 16048 + 58 * PXB, 16048 + 59 * PXB
    };

    __syncthreads();                           // X + W(0) staged

    v16i acc[2][4] = {};

    #pragma unroll
    for (int p = 0; p < 36; ++p) {             // p = tap*4 + kb-pair
        const int t = p >> 2, kp = p & 3;
        if (p < 35) {                          // stage W(p+1) into other buffer
            const int pn = p + 1;
            const int wso = (pn >> 2) * 8192 + (pn & 3) * 2048;  // literal
            const int wdo = (pn & 1) * WPHB;                     // literal
            gll16(wsrc0 + wso, wdst0 + wdo);
            gll16(wsrc1 + wso, wdst1 + wdo);
        }
        const char* wb = wbuf + (p & 1) * WPHB;
        #pragma unroll
        for (int kbl = 0; kbl < 2; ++kbl) {
            const int kb = kp * 2 + kbl;
            const int xo = xoffp[t] + kb * 32;                   // literal after unroll
            v4i xf[4], wf[2];
            #pragma unroll
            for (int ni = 0; ni < 4; ++ni)
                xf[ni] = *(const v4i*)(xs + breg[ni] + xo);
            #pragma unroll
            for (int mi = 0; mi < 2; ++mi)
                wf[mi] = *(const v4i*)(wb + ((2 * cg + mi) * 2 + kbl) * 1024 + l * 16);
            __builtin_amdgcn_s_setprio(1);
            #pragma unroll
            for (int mi = 0; mi < 2; ++mi) {
                #pragma unroll
                for (int ni = 0; ni < 4; ++ni) {
                    acc[mi][ni] = __builtin_amdgcn_mfma_i32_32x32x32_i8(
                        wf[mi], xf[ni], acc[mi][ni], 0, 0, 0);
                }
            }
            __builtin_amdgcn_s_setprio(0);
        }
        __syncthreads();                       // drains W(p+1) DMA (issued ~1 phase ago)
    }

    // C/D: col = lane&31 (spatial), row = (r&3)+8*(r>>2)+4*hi (co)
    #pragma unroll
    for (int mi = 0; mi < 2; ++mi) {
        #pragma unroll
        for (int ni = 0; ni < 4; ++ni) {
            if (!val[ni]) continue;
            const v16i c = acc[mi][ni];
            int* ob = out + outb[ni] + (cg * 64 + mi * 32 + 4 * hi) * HW2;
            #pragma unroll
            for (int rr = 0; rr < 16; ++rr) {
                __builtin_nontemporal_store(c[rr], ob + ((rr & 3) + 8 * (rr >> 2)) * HW2);
            }
        }
    }
}

// ---------- fallback: direct conv (correct, slow) ----------
__global__ void dc_naive(const int* __restrict__ x, const int* __restrict__ wt,
                         int* __restrict__ out) {
    const int idx = blockIdx.x * 256 + threadIdx.x;
    if (idx >= OUT_TOT) return;
    const int w = idx % HWDIM;
    const int h = (idx / HWDIM) % HWDIM;
    const int co = (idx / HW2) & 255;
    const int n = idx / OUT_NSTR;
    const int* xn = x + n * OUT_NSTR;
    const int* wo = wt + co * (C_IN * 9);
    int acc = 0;
    for (int ci = 0; ci < C_IN; ++ci) {
        const int* xc = xn + ci * HW2;
        const int* wc = wo + ci * 9;
        #pragma unroll
        for (int kh = 0; kh < 3; ++kh) {
            const int hh = h + kh - 1;
            if ((unsigned)hh >= HWDIM) continue;
            #pragma unroll
            for (int kw = 0; kw < 3; ++kw) {
                const int ww = w + kw - 1;
                if ((unsigned)ww >= HWDIM) continue;
                acc += xc[hh * HWDIM + ww] * wc[kh * 3 + kw];
            }
        }
    }
    out[idx] = acc;
}

extern "C" void kernel_launch(void* const* d_in, const int* in_sizes, int n_in,
                              void* d_out, int out_size, void* d_ws, size_t ws_size,
                              hipStream_t stream) {
    const int* x  = (const int*)d_in[0];
    const int* wt = (const int*)d_in[1];
    int* out = (int*)d_out;

    int chunk = 0;
    const int cand[4] = {32, 16, 8, 4};
    for (int i = 0; i < 4; ++i) {
        if ((size_t)cand[i] * XP_IMG + XP_SLACK + WP_BYTES <= ws_size) { chunk = cand[i]; break; }
    }

    if (chunk > 0) {
        char* x8 = (char*)d_ws;
        const size_t x8_bytes = (size_t)chunk * XP_IMG + XP_SLACK;
        unsigned int* wp = (unsigned int*)(x8 + x8_bytes);
        hipLaunchKernelGGL(dc_halo, dim3(chunk), dim3(256), 0, stream, (unsigned int*)x8);
        hipLaunchKernelGGL(dc_pack_w, dim3(576), dim3(256), 0, stream, wt, wp);
        for (int n0 = 0; n0 < N_IMG; n0 += chunk) {
            hipLaunchKernelGGL(dc_x_to_nhwc, dim3(chunk * HWDIM), dim3(256), 0, stream,
                               x, (unsigned int*)x8, n0);
            const int nwg = chunk * TILES_PER_IMG;
            hipLaunchKernelGGL(dc_mfma, dim3(nwg), dim3(512), LDSB, stream,
                               (const char*)x8, (const char*)wp,
                               out + (size_t)n0 * OUT_NSTR, nwg);
        }
        return;
    }

    hipLaunchKernelGGL(dc_naive, dim3((OUT_TOT + 255) / 256), dim3(256), 0, stream,
                       x, wt, out);
}

// Round 8
// 92.978 us; speedup vs baseline: 1.1370x; 1.1370x over previous
//
#include <hip/hip_runtime.h>

typedef int v4i  __attribute__((ext_vector_type(4)));
typedef int v16i __attribute__((ext_vector_type(16)));

// ---- problem constants ----
#define N_IMG   32
#define C_IN    256
#define HWDIM   56
#define HW2     3136            // 56*56
#define OUT_TOT 25690112        // 32*256*56*56
#define OUT_NSTR 802816         // 256*3136

// padded NHWC int8, PXB bytes per pixel (256 data + 16 pad)
#define PXB     272
#define PPI     3364            // 58*58 padded pixels per image
#define XP_IMG  915008          // PPI*PXB bytes per image
#define XP_SLACK 4096
// packed weights: [cb2:8][tap:9][kb:8][lane:64][16B]
#define WP_CB2STR 73728
#define WP_BYTES  589824ull

// main-kernel tiling: 64 spatial px per block -> X window 184 px
#define S_TILE  64
#define TILES_PER_IMG 49        // 3136/64 exact -> no masking
#define WIN_B   50048           // 184*272; 3 blocks/CU (150144 <= 163840)

// ---------- pre-pass A: x NCHW int32 -> padded NHWC int8 (272B/pixel) ----------
__global__ void dc_x_to_nhwc(const int* __restrict__ x, unsigned int* __restrict__ x8,
                             int n0) {
    __shared__ unsigned int lds[64 * 65];
    const int t = threadIdx.x;
    const int w = t & 63, q = t >> 6;
    const int nl = blockIdx.x / HWDIM, h = blockIdx.x % HWDIM;

    if (w < HWDIM) {
        const int* xb = x + (size_t)(n0 + nl) * OUT_NSTR + h * HWDIM + w;
        #pragma unroll
        for (int it = 0; it < 16; ++it) {
            const int cg4 = q * 16 + it;
            const int ci0 = cg4 * 4;
            unsigned v  =  ((unsigned)xb[(ci0 + 0) * HW2] & 0xff);
            v |= ((unsigned)xb[(ci0 + 1) * HW2] & 0xff) << 8;
            v |= ((unsigned)xb[(ci0 + 2) * HW2] & 0xff) << 16;
            v |= ((unsigned)xb[(ci0 + 3) * HW2] & 0xff) << 24;
            lds[w * 65 + cg4] = v;
        }
    }
    __syncthreads();
    unsigned int* ob = x8 + (size_t)nl * (PPI * (PXB / 4)) + ((h + 1) * 58 + 1) * (PXB / 4);
    #pragma unroll
    for (int it = 0; it < 14; ++it) {
        const int f = it * 256 + t;
        const int w2 = f >> 6, cg = f & 63;
        if (w2 < HWDIM) ob[w2 * (PXB / 4) + cg] = lds[w2 * 65 + cg];
    }
}

// ---------- halo-ring zero ----------
__global__ void dc_halo(unsigned int* __restrict__ x8) {
    const int nl = blockIdx.x;
    const int t = threadIdx.x;
    if (t < 228) {
        int h, w;
        if (t < 58)       { h = 0;        w = t; }
        else if (t < 116) { h = 57;       w = t - 58; }
        else if (t < 172) { h = t - 115;  w = 0; }
        else              { h = t - 171;  w = 57; }
        unsigned int* p = x8 + ((size_t)nl * PPI + h * 58 + w) * (PXB / 4);
        #pragma unroll
        for (int i = 0; i < PXB / 4; ++i) p[i] = 0;
    }
}

// ---------- pre-pass B: pack weights into per-lane fragment order ----------
__global__ void dc_pack_w(const int* __restrict__ wt, unsigned int* __restrict__ wp) {
    const int tid = blockIdx.x * 256 + threadIdx.x;  // < 147456
    const int jq = tid & 3;
    const int l  = (tid >> 2) & 63;
    const int kb = (tid >> 8) & 7;
    const int r  = tid >> 11;          // 0..71
    const int t  = r % 9;
    const int cb2 = r / 9;             // 0..7
    const int co  = cb2 * 32 + (l & 31);
    const int ci0 = kb * 32 + (l >> 5) * 16 + jq * 4;
    const int kh = t / 3, kw = t - kh * 3;
    unsigned v = 0;
    #pragma unroll
    for (int k = 0; k < 4; ++k) {
        unsigned b = (unsigned)wt[((co * C_IN + ci0 + k) * 3 + kh) * 3 + kw];
        v |= (b & 0xff) << (8 * k);
    }
    wp[tid] = v;
}

__device__ __forceinline__ void gll16(const char* g, char* l) {
    __builtin_amdgcn_global_load_lds(
        (const __attribute__((address_space(1))) unsigned int*)g,
        (__attribute__((address_space(3))) unsigned int*)l, 16, 0, 0);
}

// ---------- main kernel: 256co x 64s per block, 4 waves, 3 blocks/CU ----------
// wave = 64co x 64s (acc[2][2]); X window in LDS; barrier-free K-loop.
__global__ __launch_bounds__(256, 3) void dc_mfma(const char* __restrict__ x8,
                                                  const char* __restrict__ wp,
                                                  int* __restrict__ out, int nwg) {
    extern __shared__ __align__(16) char xs[];

    // bijective XCD swizzle (m204)
    const int bid = blockIdx.x;
    const int q = nwg >> 3, r = nwg & 7;
    const int xcd = bid & 7, bidx = bid >> 3;
    const int wgid = (xcd < r ? xcd * (q + 1) : r * (q + 1) + (xcd - r) * q) + bidx;

    const int nl = wgid / TILES_PER_IMG, st = wgid - nl * TILES_PER_IMG;

    const int tid = threadIdx.x;
    const int l = tid & 63, wid = tid >> 6;
    const int lane31 = l & 31, hi = l >> 5;

    // stage window: padded pixels [p0, p0+184) of this image; p0 = h0*58 + w0
    const int hw0 = st * S_TILE;
    const int h0 = hw0 / HWDIM, w0 = hw0 - h0 * HWDIM;
    const int p0 = h0 * 58 + w0;
    const char* gsrc = x8 + (size_t)nl * XP_IMG + (size_t)p0 * PXB;

    #pragma unroll
    for (int c = 0; c < 13; ++c) {             // 13*256*16 = 53248 >= 50048
        const int off = (c * 256 + tid) * 16;
        if (off < WIN_B) gll16(gsrc + off, xs + off);
    }

    // per-s-fragment setup (2 frags of 32 spatial) while DMA flies
    int breg[2], outb[2];
    #pragma unroll
    for (int ni = 0; ni < 2; ++ni) {
        const int hw = hw0 + ni * 32 + lane31;
        const int h = hw / HWDIM, w = hw - h * HWDIM;
        const int p = (h + 1) * 58 + (w + 1);
        breg[ni] = (p - p0) * PXB + hi * 16 - 16048;   // >= 0 after +xoffp
        outb[ni] = nl * OUT_NSTR + hw;
    }

    // wave wid owns co = wid*64 .. +63  (cb2 = wid*2, wid*2+1)
    const char* wb0 = wp + (wid * 2) * WP_CB2STR + l * 16;
    const char* wb1 = wb0 + WP_CB2STR;

    const int xoffp[9] = {
        16048 - 59 * PXB, 16048 - 58 * PXB, 16048 - 57 * PXB,
        16048 - 1 * PXB,  16048,            16048 + 1 * PXB,
        16048 + 57 * PXB, 16048 + 58 * PXB, 16048 + 59 * PXB
    };

    __syncthreads();                           // X staged; no more barriers

    v16i acc[2][2] = {};
    v4i wa[4][2];                              // depth-3 W prefetch ring
    v4i xb[2][2];                              // depth-1 X prefetch ring

    wa[0][0] = *(const v4i*)(wb0);
    wa[0][1] = *(const v4i*)(wb1);
    wa[1][0] = *(const v4i*)(wb0 + 1024);
    wa[1][1] = *(const v4i*)(wb1 + 1024);
    wa[2][0] = *(const v4i*)(wb0 + 2048);
    wa[2][1] = *(const v4i*)(wb1 + 2048);
    xb[0][0] = *(const v4i*)(xs + breg[0] + xoffp[0]);
    xb[0][1] = *(const v4i*)(xs + breg[1] + xoffp[0]);

    #pragma unroll
    for (int j = 0; j < 72; ++j) {             // j = tap*8 + kb; all idx static
        const int jc = j & 3;
        const int pc = j & 1;
        if (j + 3 < 72) {
            const int jn = (j + 3) & 3;
            wa[jn][0] = *(const v4i*)(wb0 + (j + 3) * 1024);
            wa[jn][1] = *(const v4i*)(wb1 + (j + 3) * 1024);
        }
        if (j + 1 < 72) {
            const int t1 = (j + 1) >> 3, kb1 = (j + 1) & 7;
            const int xo = xoffp[t1] + kb1 * 32;
            xb[pc ^ 1][0] = *(const v4i*)(xs + breg[0] + xo);
            xb[pc ^ 1][1] = *(const v4i*)(xs + breg[1] + xo);
        }
        __builtin_amdgcn_s_setprio(1);
        acc[0][0] = __builtin_amdgcn_mfma_i32_32x32x32_i8(wa[jc][0], xb[pc][0], acc[0][0], 0, 0, 0);
        acc[0][1] = __builtin_amdgcn_mfma_i32_32x32x32_i8(wa[jc][0], xb[pc][1], acc[0][1], 0, 0, 0);
        acc[1][0] = __builtin_amdgcn_mfma_i32_32x32x32_i8(wa[jc][1], xb[pc][0], acc[1][0], 0, 0, 0);
        acc[1][1] = __builtin_amdgcn_mfma_i32_32x32x32_i8(wa[jc][1], xb[pc][1], acc[1][1], 0, 0, 0);
        __builtin_amdgcn_s_setprio(0);
    }

    // C/D: col = lane&31 (spatial), row = (r&3)+8*(r>>2)+4*hi (co)
    #pragma unroll
    for (int mi = 0; mi < 2; ++mi) {
        #pragma unroll
        for (int ni = 0; ni < 2; ++ni) {
            const v16i c = acc[mi][ni];
            int* ob = out + outb[ni] + (wid * 64 + mi * 32 + 4 * hi) * HW2;
            #pragma unroll
            for (int rr = 0; rr < 16; ++rr) {
                __builtin_nontemporal_store(c[rr], ob + ((rr & 3) + 8 * (rr >> 2)) * HW2);
            }
        }
    }
}

// ---------- fallback: direct conv (correct, slow) ----------
__global__ void dc_naive(const int* __restrict__ x, const int* __restrict__ wt,
                         int* __restrict__ out) {
    const int idx = blockIdx.x * 256 + threadIdx.x;
    if (idx >= OUT_TOT) return;
    const int w = idx % HWDIM;
    const int h = (idx / HWDIM) % HWDIM;
    const int co = (idx / HW2) & 255;
    const int n = idx / OUT_NSTR;
    const int* xn = x + n * OUT_NSTR;
    const int* wo = wt + co * (C_IN * 9);
    int acc = 0;
    for (int ci = 0; ci < C_IN; ++ci) {
        const int* xc = xn + ci * HW2;
        const int* wc = wo + ci * 9;
        #pragma unroll
        for (int kh = 0; kh < 3; ++kh) {
            const int hh = h + kh - 1;
            if ((unsigned)hh >= HWDIM) continue;
            #pragma unroll
            for (int kw = 0; kw < 3; ++kw) {
                const int ww = w + kw - 1;
                if ((unsigned)ww >= HWDIM) continue;
                acc += xc[hh * HWDIM + ww] * wc[kh * 3 + kw];
            }
        }
    }
    out[idx] = acc;
}

extern "C" void kernel_launch(void* const* d_in, const int* in_sizes, int n_in,
                              void* d_out, int out_size, void* d_ws, size_t ws_size,
                              hipStream_t stream) {
    const int* x  = (const int*)d_in[0];
    const int* wt = (const int*)d_in[1];
    int* out = (int*)d_out;

    int chunk = 0;
    const int cand[4] = {32, 16, 8, 4};
    for (int i = 0; i < 4; ++i) {
        if ((size_t)cand[i] * XP_IMG + XP_SLACK + WP_BYTES <= ws_size) { chunk = cand[i]; break; }
    }

    if (chunk > 0) {
        char* x8 = (char*)d_ws;
        const size_t x8_bytes = (size_t)chunk * XP_IMG + XP_SLACK;
        unsigned int* wp = (unsigned int*)(x8 + x8_bytes);
        hipLaunchKernelGGL(dc_halo, dim3(chunk), dim3(256), 0, stream, (unsigned int*)x8);
        hipLaunchKernelGGL(dc_pack_w, dim3(576), dim3(256), 0, stream, wt, wp);
        for (int n0 = 0; n0 < N_IMG; n0 += chunk) {
            hipLaunchKernelGGL(dc_x_to_nhwc, dim3(chunk * HWDIM), dim3(256), 0, stream,
                               x, (unsigned int*)x8, n0);
            const int nwg = chunk * TILES_PER_IMG;
            hipLaunchKernelGGL(dc_mfma, dim3(nwg), dim3(256), WIN_B, stream,
                               (const char*)x8, (const char*)wp,
                               out + (size_t)n0 * OUT_NSTR, nwg);
        }
        return;
    }

    hipLaunchKernelGGL(dc_naive, dim3((OUT_TOT + 255) / 256), dim3(256), 0, stream,
                       x, wt, out);
}

// Round 9
// 92.937 us; speedup vs baseline: 1.1375x; 1.0004x over previous
//
#include <hip/hip_runtime.h>

typedef int v4i  __attribute__((ext_vector_type(4)));
typedef int v16i __attribute__((ext_vector_type(16)));

// ---- problem constants ----
#define N_IMG   32
#define C_IN    256
#define HWDIM   56
#define HW2     3136            // 56*56
#define OUT_TOT 25690112        // 32*256*56*56
#define OUT_NSTR 802816         // 256*3136

// padded NHWC int8, PXB bytes per pixel (256 data + 16 pad; 16B-aligned for gll16)
#define PXB     272
#define PPI     3364            // 58*58 padded pixels per image
#define XP_IMG  915008          // PPI*PXB bytes per image
#define XP_SLACK 4096
// packed weights: [cb2:8][tap:9][kb:8][lane:64][16B]
#define WP_CB2STR 73728
#define WP_BYTES  589824ull

// main-kernel tiling: 64 spatial px per block -> X window 184 px
#define S_TILE  64
#define TILES_PER_IMG 49        // 3136/64 exact -> no masking
#define WIN_B   50048           // 184*272; target 3 blocks/CU

// ---------- pre-pass A: x NCHW int32 -> padded NHWC int8 (272B/pixel) ----------
__global__ void dc_x_to_nhwc(const int* __restrict__ x, unsigned int* __restrict__ x8,
                             int n0) {
    __shared__ unsigned int lds[64 * 65];
    const int t = threadIdx.x;
    const int w = t & 63, q = t >> 6;
    const int nl = blockIdx.x / HWDIM, h = blockIdx.x % HWDIM;

    if (w < HWDIM) {
        const int* xb = x + (size_t)(n0 + nl) * OUT_NSTR + h * HWDIM + w;
        #pragma unroll
        for (int it = 0; it < 16; ++it) {
            const int cg4 = q * 16 + it;
            const int ci0 = cg4 * 4;
            unsigned v  =  ((unsigned)xb[(ci0 + 0) * HW2] & 0xff);
            v |= ((unsigned)xb[(ci0 + 1) * HW2] & 0xff) << 8;
            v |= ((unsigned)xb[(ci0 + 2) * HW2] & 0xff) << 16;
            v |= ((unsigned)xb[(ci0 + 3) * HW2] & 0xff) << 24;
            lds[w * 65 + cg4] = v;
        }
    }
    __syncthreads();
    unsigned int* ob = x8 + (size_t)nl * (PPI * (PXB / 4)) + ((h + 1) * 58 + 1) * (PXB / 4);
    #pragma unroll
    for (int it = 0; it < 14; ++it) {
        const int f = it * 256 + t;
        const int w2 = f >> 6, cg = f & 63;
        if (w2 < HWDIM) ob[w2 * (PXB / 4) + cg] = lds[w2 * 65 + cg];
    }
}

// ---------- halo-ring zero ----------
__global__ void dc_halo(unsigned int* __restrict__ x8) {
    const int nl = blockIdx.x;
    const int t = threadIdx.x;
    if (t < 228) {
        int h, w;
        if (t < 58)       { h = 0;        w = t; }
        else if (t < 116) { h = 57;       w = t - 58; }
        else if (t < 172) { h = t - 115;  w = 0; }
        else              { h = t - 171;  w = 57; }
        unsigned int* p = x8 + ((size_t)nl * PPI + h * 58 + w) * (PXB / 4);
        #pragma unroll
        for (int i = 0; i < PXB / 4; ++i) p[i] = 0;
    }
}

// ---------- pre-pass B: pack weights into per-lane fragment order ----------
__global__ void dc_pack_w(const int* __restrict__ wt, unsigned int* __restrict__ wp) {
    const int tid = blockIdx.x * 256 + threadIdx.x;  // < 147456
    const int jq = tid & 3;
    const int l  = (tid >> 2) & 63;
    const int kb = (tid >> 8) & 7;
    const int r  = tid >> 11;          // 0..71
    const int t  = r % 9;
    const int cb2 = r / 9;             // 0..7
    const int co  = cb2 * 32 + (l & 31);
    const int ci0 = kb * 32 + (l >> 5) * 16 + jq * 4;
    const int kh = t / 3, kw = t - kh * 3;
    unsigned v = 0;
    #pragma unroll
    for (int k = 0; k < 4; ++k) {
        unsigned b = (unsigned)wt[((co * C_IN + ci0 + k) * 3 + kh) * 3 + kw];
        v |= (b & 0xff) << (8 * k);
    }
    wp[tid] = v;
}

__device__ __forceinline__ void gll16(const char* g, char* l) {
    __builtin_amdgcn_global_load_lds(
        (const __attribute__((address_space(1))) unsigned int*)g,
        (__attribute__((address_space(3))) unsigned int*)l, 16, 0, 0);
}

// ---------- main kernel: 256co x 64s per block, 4 waves, 3 blocks/CU ----------
// wave = 64co x 64s (acc[2][2]); X window in LDS; barrier-free K-loop.
// R9 change: W register prefetch ring depth 3 -> 6 (8 slots).
__global__ __launch_bounds__(256, 3) void dc_mfma(const char* __restrict__ x8,
                                                  const char* __restrict__ wp,
                                                  int* __restrict__ out, int nwg) {
    extern __shared__ __align__(16) char xs[];

    // bijective XCD swizzle (m204)
    const int bid = blockIdx.x;
    const int q = nwg >> 3, r = nwg & 7;
    const int xcd = bid & 7, bidx = bid >> 3;
    const int wgid = (xcd < r ? xcd * (q + 1) : r * (q + 1) + (xcd - r) * q) + bidx;

    const int nl = wgid / TILES_PER_IMG, st = wgid - nl * TILES_PER_IMG;

    const int tid = threadIdx.x;
    const int l = tid & 63, wid = tid >> 6;
    const int lane31 = l & 31, hi = l >> 5;

    // stage window: padded pixels [p0, p0+184) of this image; p0 = h0*58 + w0
    const int hw0 = st * S_TILE;
    const int h0 = hw0 / HWDIM, w0 = hw0 - h0 * HWDIM;
    const int p0 = h0 * 58 + w0;
    const char* gsrc = x8 + (size_t)nl * XP_IMG + (size_t)p0 * PXB;

    #pragma unroll
    for (int c = 0; c < 13; ++c) {             // 13*256*16 = 53248 >= 50048
        const int off = (c * 256 + tid) * 16;
        if (off < WIN_B) gll16(gsrc + off, xs + off);
    }

    // per-s-fragment setup (2 frags of 32 spatial) while DMA flies
    int breg[2], outb[2];
    #pragma unroll
    for (int ni = 0; ni < 2; ++ni) {
        const int hw = hw0 + ni * 32 + lane31;
        const int h = hw / HWDIM, w = hw - h * HWDIM;
        const int p = (h + 1) * 58 + (w + 1);
        breg[ni] = (p - p0) * PXB + hi * 16 - 16048;   // >= 0 after +xoffp
        outb[ni] = nl * OUT_NSTR + hw;
    }

    // wave wid owns co = wid*64 .. +63  (cb2 = wid*2, wid*2+1)
    const char* wb0 = wp + (wid * 2) * WP_CB2STR + l * 16;
    const char* wb1 = wb0 + WP_CB2STR;

    const int xoffp[9] = {
        16048 - 59 * PXB, 16048 - 58 * PXB, 16048 - 57 * PXB,
        16048 - 1 * PXB,  16048,            16048 + 1 * PXB,
        16048 + 57 * PXB, 16048 + 58 * PXB, 16048 + 59 * PXB
    };

    // W ring prologue: depth 6 (issued before the barrier; drained by its vmcnt(0))
    v16i acc[2][2] = {};
    v4i wa[8][2];                              // 8-slot ring, prefetch distance 6
    v4i xb[2][2];                              // depth-1 X prefetch ring

    #pragma unroll
    for (int d = 0; d < 6; ++d) {
        wa[d][0] = *(const v4i*)(wb0 + d * 1024);
        wa[d][1] = *(const v4i*)(wb1 + d * 1024);
    }

    __syncthreads();                           // X staged; no more barriers

    xb[0][0] = *(const v4i*)(xs + breg[0] + xoffp[0]);
    xb[0][1] = *(const v4i*)(xs + breg[1] + xoffp[0]);

    #pragma unroll
    for (int j = 0; j < 72; ++j) {             // j = tap*8 + kb; all idx static
        const int jc = j & 7;
        const int pc = j & 1;
        if (j + 6 < 72) {
            const int jn = (j + 6) & 7;
            wa[jn][0] = *(const v4i*)(wb0 + (j + 6) * 1024);
            wa[jn][1] = *(const v4i*)(wb1 + (j + 6) * 1024);
        }
        if (j + 1 < 72) {
            const int t1 = (j + 1) >> 3, kb1 = (j + 1) & 7;
            const int xo = xoffp[t1] + kb1 * 32;
            xb[pc ^ 1][0] = *(const v4i*)(xs + breg[0] + xo);
            xb[pc ^ 1][1] = *(const v4i*)(xs + breg[1] + xo);
        }
        __builtin_amdgcn_s_setprio(1);
        acc[0][0] = __builtin_amdgcn_mfma_i32_32x32x32_i8(wa[jc][0], xb[pc][0], acc[0][0], 0, 0, 0);
        acc[0][1] = __builtin_amdgcn_mfma_i32_32x32x32_i8(wa[jc][0], xb[pc][1], acc[0][1], 0, 0, 0);
        acc[1][0] = __builtin_amdgcn_mfma_i32_32x32x32_i8(wa[jc][1], xb[pc][0], acc[1][0], 0, 0, 0);
        acc[1][1] = __builtin_amdgcn_mfma_i32_32x32x32_i8(wa[jc][1], xb[pc][1], acc[1][1], 0, 0, 0);
        __builtin_amdgcn_s_setprio(0);
    }

    // C/D: col = lane&31 (spatial), row = (r&3)+8*(r>>2)+4*hi (co)
    #pragma unroll
    for (int mi = 0; mi < 2; ++mi) {
        #pragma unroll
        for (int ni = 0; ni < 2; ++ni) {
            const v16i c = acc[mi][ni];
            int* ob = out + outb[ni] + (wid * 64 + mi * 32 + 4 * hi) * HW2;
            #pragma unroll
            for (int rr = 0; rr < 16; ++rr) {
                __builtin_nontemporal_store(c[rr], ob + ((rr & 3) + 8 * (rr >> 2)) * HW2);
            }
        }
    }
}

// ---------- fallback: direct conv (correct, slow) ----------
__global__ void dc_naive(const int* __restrict__ x, const int* __restrict__ wt,
                         int* __restrict__ out) {
    const int idx = blockIdx.x * 256 + threadIdx.x;
    if (idx >= OUT_TOT) return;
    const int w = idx % HWDIM;
    const int h = (idx / HWDIM) % HWDIM;
    const int co = (idx / HW2) & 255;
    const int n = idx / OUT_NSTR;
    const int* xn = x + n * OUT_NSTR;
    const int* wo = wt + co * (C_IN * 9);
    int acc = 0;
    for (int ci = 0; ci < C_IN; ++ci) {
        const int* xc = xn + ci * HW2;
        const int* wc = wo + ci * 9;
        #pragma unroll
        for (int kh = 0; kh < 3; ++kh) {
            const int hh = h + kh - 1;
            if ((unsigned)hh >= HWDIM) continue;
            #pragma unroll
            for (int kw = 0; kw < 3; ++kw) {
                const int ww = w + kw - 1;
                if ((unsigned)ww >= HWDIM) continue;
                acc += xc[hh * HWDIM + ww] * wc[kh * 3 + kw];
            }
        }
    }
    out[idx] = acc;
}

extern "C" void kernel_launch(void* const* d_in, const int* in_sizes, int n_in,
                              void* d_out, int out_size, void* d_ws, size_t ws_size,
                              hipStream_t stream) {
    const int* x  = (const int*)d_in[0];
    const int* wt = (const int*)d_in[1];
    int* out = (int*)d_out;

    int chunk = 0;
    const int cand[4] = {32, 16, 8, 4};
    for (int i = 0; i < 4; ++i) {
        if ((size_t)cand[i] * XP_IMG + XP_SLACK + WP_BYTES <= ws_size) { chunk = cand[i]; break; }
    }

    if (chunk > 0) {
        char* x8 = (char*)d_ws;
        const size_t x8_bytes = (size_t)chunk * XP_IMG + XP_SLACK;
        unsigned int* wp = (unsigned int*)(x8 + x8_bytes);
        hipLaunchKernelGGL(dc_halo, dim3(chunk), dim3(256), 0, stream, (unsigned int*)x8);
        hipLaunchKernelGGL(dc_pack_w, dim3(576), dim3(256), 0, stream, wt, wp);
        for (int n0 = 0; n0 < N_IMG; n0 += chunk) {
            hipLaunchKernelGGL(dc_x_to_nhwc, dim3(chunk * HWDIM), dim3(256), 0, stream,
                               x, (unsigned int*)x8, n0);
            const int nwg = chunk * TILES_PER_IMG;
            hipLaunchKernelGGL(dc_mfma, dim3(nwg), dim3(256), WIN_B, stream,
                               (const char*)x8, (const char*)wp,
                               out + (size_t)n0 * OUT_NSTR, nwg);
        }
        return;
    }

    hipLaunchKernelGGL(dc_naive, dim3((OUT_TOT + 255) / 256), dim3(256), 0, stream,
                       x, wt, out);
}